// Round 16
// baseline (188.480 us; speedup 1.0000x reference)
//
#include <hip/hip_runtime.h>
#include <hip/hip_bf16.h>
#include <math.h>

#define N_NODES 100000
#define N_EDGES 800000
#define IN_C 96
#define OUT_C 64
#define C4 (IN_C / 4)   // 24 float4 chunks per node
#define XPAD 104        // padded LDS row stride in bf16 elems

typedef __attribute__((ext_vector_type(8))) short bf16x8;
typedef __attribute__((ext_vector_type(4))) float f32x4;

// bf16 helpers (manual, deterministic RNE)
__device__ __forceinline__ unsigned short f2bf(float f) {
    unsigned u = __float_as_uint(f);
    unsigned r = 0x7FFFu + ((u >> 16) & 1u);
    return (unsigned short)((u + r) >> 16);
}
__device__ __forceinline__ unsigned pack2bf(float a, float b) {
    return (unsigned)f2bf(a) | ((unsigned)f2bf(b) << 16);
}
// packed csr entry: [src:17][dinv_src_bf15:15]
__device__ __forceinline__ float dec_w(unsigned p) {
    return __uint_as_float((p & 0x7FFFu) << 16);
}
// fp8 e4m3 (OCP on gfx950) via HW converts
__device__ __forceinline__ unsigned char f2fp8(float f) {
    return (unsigned char)(__builtin_amdgcn_cvt_pk_fp8_f32(f, f, 0, false) & 0xFF);
}

// ================= shared linear block body (MFMA x@W^T for 64 nodes) =================
__device__ __forceinline__ void linear_block(int g, int tid,
                                             const float* __restrict__ x,
                                             const float* __restrict__ W,
                                             unsigned char* __restrict__ y, int n,
                                             unsigned short* wbf) {
    int lane = tid & 63;
    int wv = tid >> 6;
    int node0 = g * 64;

    // stage W only (13.3KB)
    for (int i = tid; i < 64 * C4; i += 256) {
        int o = i / C4;
        int c4 = i - o * C4;
        float4 v = ((const float4*)(W + (size_t)o * IN_C))[c4];
        uint2 pk;
        pk.x = pack2bf(v.x, v.y);
        pk.y = pack2bf(v.z, v.w);
        *(uint2*)&wbf[o * XPAD + c4 * 4] = pk;
    }
    __syncthreads();

    int l16 = lane & 15;
    int quad = lane >> 4;

    // A-row for this lane: loaded straight from global (f32 -> bf16, same RNE)
    int arow = node0 + wv * 16 + l16;
    const float* xr = x + (size_t)((arow < n) ? arow : 0) * IN_C + quad * 8;

    f32x4 acc0 = {0.f, 0.f, 0.f, 0.f};
    f32x4 acc1 = {0.f, 0.f, 0.f, 0.f};
    f32x4 acc2 = {0.f, 0.f, 0.f, 0.f};
    f32x4 acc3 = {0.f, 0.f, 0.f, 0.f};

#pragma unroll
    for (int kc = 0; kc < 3; ++kc) {
        float4 v0 = ((const float4*)(xr + kc * 32))[0];
        float4 v1 = ((const float4*)(xr + kc * 32))[1];
        union { bf16x8 v; unsigned u[4]; } au;
        au.u[0] = pack2bf(v0.x, v0.y);
        au.u[1] = pack2bf(v0.z, v0.w);
        au.u[2] = pack2bf(v1.x, v1.y);
        au.u[3] = pack2bf(v1.z, v1.w);
        bf16x8 a = au.v;
        bf16x8 b0 = *(const bf16x8*)&wbf[(0 * 16 + l16) * XPAD + kc * 32 + quad * 8];
        bf16x8 b1 = *(const bf16x8*)&wbf[(1 * 16 + l16) * XPAD + kc * 32 + quad * 8];
        bf16x8 b2 = *(const bf16x8*)&wbf[(2 * 16 + l16) * XPAD + kc * 32 + quad * 8];
        bf16x8 b3 = *(const bf16x8*)&wbf[(3 * 16 + l16) * XPAD + kc * 32 + quad * 8];
        acc0 = __builtin_amdgcn_mfma_f32_16x16x32_bf16(a, b0, acc0, 0, 0, 0);
        acc1 = __builtin_amdgcn_mfma_f32_16x16x32_bf16(a, b1, acc1, 0, 0, 0);
        acc2 = __builtin_amdgcn_mfma_f32_16x16x32_bf16(a, b2, acc2, 0, 0, 0);
        acc3 = __builtin_amdgcn_mfma_f32_16x16x32_bf16(a, b3, acc3, 0, 0, 0);
    }

#pragma unroll
    for (int r = 0; r < 4; ++r) {
        int node = node0 + wv * 16 + quad * 4 + r;
        if (node < n) {
            size_t base = (size_t)node * OUT_C + l16;
            y[base + 0]  = f2fp8(acc0[r]);
            y[base + 16] = f2fp8(acc1[r]);
            y[base + 32] = f2fp8(acc2[r]);
            y[base + 48] = f2fp8(acc3[r]);
        }
    }
}

// ================= count (+ first half of linear), interleaved 2:1 =================
__global__ void count_linear_kernel(const int* __restrict__ col, int* __restrict__ cnt,
                                    unsigned short* __restrict__ eidx,
                                    unsigned* __restrict__ csr, int e,
                                    const float* __restrict__ x, const float* __restrict__ W,
                                    unsigned char* __restrict__ y, int n, int lin_half) {
    __shared__ unsigned short wbf[64 * XPAD];
    int g = blockIdx.x / 3;
    int r3 = blockIdx.x - g * 3;
    if (r3 != 2) {
        int i = (g * 2 + r3) * 256 + threadIdx.x;
        if (i < 16) csr[e + i] = 0u;   // tail zeroing for unpredicated gather loads
        if (i < e) {
            int slot = atomicAdd(&cnt[col[i]], 1);
            eidx[i] = (unsigned short)slot;
        }
        return;
    }
    if (g >= lin_half) return;
    linear_block(g, threadIdx.x, x, W, y, n, wbf);
}

// ================= fused single-pass scan: atomic chunk-offset assignment =================
// Each block scans its 512-elem chunk of cnt locally, claims a global base via
// ONE atomicAdd(total, chunkSum), and writes row_start/dinv. row_start is NOT
// globally monotone (chunk placement non-deterministic), which is fine:
// fill uses row_start[c]+eidx[i]; gather uses end = beg + cnt[node].
// Per-node slot order is preserved -> per-node accumulation order unchanged
// -> output bit-identical to the two-pass scan.
__global__ void scan_fused_kernel(const int* __restrict__ cnt, int* __restrict__ total,
                                  int* __restrict__ row_start, float* __restrict__ dinv,
                                  int n) {
    __shared__ int ss[256];
    __shared__ int chunk_base;
    int t = threadIdx.x;
    int base = blockIdx.x << 9;

    // inclusive scan of first half [base, base+256)
    int i0 = base + t;
    int v0 = (i0 < n) ? cnt[i0] : 0;
    int r0 = v0;
    ss[t] = v0;
    __syncthreads();
    for (int off = 1; off < 256; off <<= 1) {
        int tmp = (t >= off) ? ss[t - off] : 0;
        __syncthreads();
        r0 += tmp;
        ss[t] = r0;
        __syncthreads();
    }
    int total0 = ss[255];
    __syncthreads();

    // inclusive scan of second half [base+256, base+512)
    int i1 = base + 256 + t;
    int v1 = (i1 < n) ? cnt[i1] : 0;
    int r1 = v1;
    ss[t] = v1;
    __syncthreads();
    for (int off = 1; off < 256; off <<= 1) {
        int tmp = (t >= off) ? ss[t - off] : 0;
        __syncthreads();
        r1 += tmp;
        ss[t] = r1;
        __syncthreads();
    }
    int total1 = ss[255];

    if (t == 0) chunk_base = atomicAdd(total, total0 + total1);
    __syncthreads();
    int b0 = chunk_base;

    if (i0 < n) { row_start[i0] = b0 + r0 - v0;          dinv[i0] = rsqrtf((float)v0 + 1.0f); }
    if (i1 < n) { row_start[i1] = b0 + total0 + r1 - v1; dinv[i1] = rsqrtf((float)v1 + 1.0f); }
}

// ================= fill (+ second half of linear), interleaved 2:1 =================
__global__ void fill_linear_kernel(const int* __restrict__ row, const int* __restrict__ col,
                                   const float* __restrict__ dinv,
                                   const int* __restrict__ row_start,
                                   const unsigned short* __restrict__ eidx,
                                   unsigned* __restrict__ csr, int e,
                                   const float* __restrict__ x, const float* __restrict__ W,
                                   unsigned char* __restrict__ y, int n,
                                   int lin_half, int nb_lin) {
    __shared__ unsigned short wbf[64 * XPAD];

    int g = blockIdx.x / 3;
    int r3 = blockIdx.x - g * 3;
    if (r3 != 2) {
        int i = (g * 2 + r3) * 256 + threadIdx.x;
        if (i < e) {
            int r = row[i];
            int c = col[i];
            int pos = row_start[c] + (int)eidx[i];
            csr[pos] = ((unsigned)r << 15) | (unsigned)f2bf(dinv[r]);
        }
        return;
    }
    int gl = lin_half + g;
    if (gl >= nb_lin) return;
    linear_block(gl, threadIdx.x, x, W, y, n, wbf);
}

// ================= gather hop: 16 lanes per node, fp8 rows, 4 nodes per wave =================
// end = beg + cnt[node] (row_start is non-monotone after the atomic scan).
// Row = 64 fp8 ch = 64B; lane c loads ONE dword = channels 4c..4c+3.
// csr loads unpredicated (zeroed tail), ENTRY masked. Accumulation bank order
// unchanged (self->bank0, slot k->bank k&3).

#define GACC(EA, EB, EC, ED, w, v) \
    EA += (w) * __builtin_amdgcn_cvt_f32_fp8((int)(v), 0); \
    EB += (w) * __builtin_amdgcn_cvt_f32_fp8((int)(v), 1); \
    EC += (w) * __builtin_amdgcn_cvt_f32_fp8((int)(v), 2); \
    ED += (w) * __builtin_amdgcn_cvt_f32_fp8((int)(v), 3);

template <bool FINAL>
__global__ void gather_kernel(const unsigned char* __restrict__ src,
                              unsigned char* __restrict__ dst_fp8,
                              float* __restrict__ dst_f32,
                              const int* __restrict__ row_start,
                              const int* __restrict__ cnt,
                              const unsigned* __restrict__ csr,
                              const float* __restrict__ dinv, const float* __restrict__ bias,
                              int n) {
    int node = blockIdx.x * (blockDim.x >> 4) + (threadIdx.x >> 4);
    if (node >= n) return;
    int c = threadIdx.x & 15;                // dword index: channels 4c..4c+3
    const unsigned* srcp = (const unsigned*)src;

    int beg = row_start[node];
    int end = beg + cnt[node];

    // self-loop
    unsigned pv = srcp[(size_t)node * 16 + c];
    float s = dinv[node];
    float ss = s * s;

    float e0a = 0.f, e0b = 0.f, e0c = 0.f, e0d = 0.f;
    float e1a = 0.f, e1b = 0.f, e1c = 0.f, e1d = 0.f;
    float e2a = 0.f, e2b = 0.f, e2c = 0.f, e2d = 0.f;
    float e3a = 0.f, e3b = 0.f, e3c = 0.f, e3d = 0.f;
    GACC(e0a, e0b, e0c, e0d, ss, pv)

    for (int j0 = beg; j0 < end; j0 += 16) {
        unsigned t0 = csr[j0];
        unsigned t1 = csr[j0 + 1];
        unsigned t2 = csr[j0 + 2];
        unsigned t3 = csr[j0 + 3];
        unsigned t4 = csr[j0 + 4];
        unsigned t5 = csr[j0 + 5];
        unsigned t6 = csr[j0 + 6];
        unsigned t7 = csr[j0 + 7];
        unsigned t8 = csr[j0 + 8];
        unsigned t9 = csr[j0 + 9];
        unsigned ta = csr[j0 + 10];
        unsigned tb = csr[j0 + 11];
        unsigned tc = csr[j0 + 12];
        unsigned td = csr[j0 + 13];
        unsigned te = csr[j0 + 14];
        unsigned tf = csr[j0 + 15];
        unsigned p0 = (j0 + 0  < end) ? t0 : 0u;
        unsigned p1 = (j0 + 1  < end) ? t1 : 0u;
        unsigned p2 = (j0 + 2  < end) ? t2 : 0u;
        unsigned p3 = (j0 + 3  < end) ? t3 : 0u;
        unsigned p4 = (j0 + 4  < end) ? t4 : 0u;
        unsigned p5 = (j0 + 5  < end) ? t5 : 0u;
        unsigned p6 = (j0 + 6  < end) ? t6 : 0u;
        unsigned p7 = (j0 + 7  < end) ? t7 : 0u;
        unsigned p8 = (j0 + 8  < end) ? t8 : 0u;
        unsigned p9 = (j0 + 9  < end) ? t9 : 0u;
        unsigned pa = (j0 + 10 < end) ? ta : 0u;
        unsigned pb = (j0 + 11 < end) ? tb : 0u;
        unsigned pc = (j0 + 12 < end) ? tc : 0u;
        unsigned pd = (j0 + 13 < end) ? td : 0u;
        unsigned pe = (j0 + 14 < end) ? te : 0u;
        unsigned pf = (j0 + 15 < end) ? tf : 0u;
        unsigned v0 = srcp[(size_t)(p0 >> 15) * 16 + c];
        unsigned v1 = srcp[(size_t)(p1 >> 15) * 16 + c];
        unsigned v2 = srcp[(size_t)(p2 >> 15) * 16 + c];
        unsigned v3 = srcp[(size_t)(p3 >> 15) * 16 + c];
        unsigned v4 = srcp[(size_t)(p4 >> 15) * 16 + c];
        unsigned v5 = srcp[(size_t)(p5 >> 15) * 16 + c];
        unsigned v6 = srcp[(size_t)(p6 >> 15) * 16 + c];
        unsigned v7 = srcp[(size_t)(p7 >> 15) * 16 + c];
        unsigned v8 = srcp[(size_t)(p8 >> 15) * 16 + c];
        unsigned v9 = srcp[(size_t)(p9 >> 15) * 16 + c];
        unsigned va = srcp[(size_t)(pa >> 15) * 16 + c];
        unsigned vb = srcp[(size_t)(pb >> 15) * 16 + c];
        unsigned vc = srcp[(size_t)(pc >> 15) * 16 + c];
        unsigned vd = srcp[(size_t)(pd >> 15) * 16 + c];
        unsigned ve = srcp[(size_t)(pe >> 15) * 16 + c];
        unsigned vf = srcp[(size_t)(pf >> 15) * 16 + c];
        float w0 = dec_w(p0) * s, w1 = dec_w(p1) * s, w2 = dec_w(p2) * s, w3 = dec_w(p3) * s;
        float w4 = dec_w(p4) * s, w5 = dec_w(p5) * s, w6 = dec_w(p6) * s, w7 = dec_w(p7) * s;
        float w8 = dec_w(p8) * s, w9 = dec_w(p9) * s, wa = dec_w(pa) * s, wb = dec_w(pb) * s;
        float wc = dec_w(pc) * s, wd = dec_w(pd) * s, we = dec_w(pe) * s, wf = dec_w(pf) * s;
        GACC(e0a, e0b, e0c, e0d, w0, v0)
        GACC(e1a, e1b, e1c, e1d, w1, v1)
        GACC(e2a, e2b, e2c, e2d, w2, v2)
        GACC(e3a, e3b, e3c, e3d, w3, v3)
        GACC(e0a, e0b, e0c, e0d, w4, v4)
        GACC(e1a, e1b, e1c, e1d, w5, v5)
        GACC(e2a, e2b, e2c, e2d, w6, v6)
        GACC(e3a, e3b, e3c, e3d, w7, v7)
        GACC(e0a, e0b, e0c, e0d, w8, v8)
        GACC(e1a, e1b, e1c, e1d, w9, v9)
        GACC(e2a, e2b, e2c, e2d, wa, va)
        GACC(e3a, e3b, e3c, e3d, wb, vb)
        GACC(e0a, e0b, e0c, e0d, wc, vc)
        GACC(e1a, e1b, e1c, e1d, wd, vd)
        GACC(e2a, e2b, e2c, e2d, we, ve)
        GACC(e3a, e3b, e3c, e3d, wf, vf)
    }
    float a0 = (e0a + e1a) + (e2a + e3a);
    float a1 = (e0b + e1b) + (e2b + e3b);
    float a2 = (e0c + e1c) + (e2c + e3c);
    float a3 = (e0d + e1d) + (e2d + e3d);

    if (FINAL) {
        float4 bb = ((const float4*)bias)[c];
        float4 o;
        o.x = 1.0f / (1.0f + __expf(-(a0 + bb.x)));
        o.y = 1.0f / (1.0f + __expf(-(a1 + bb.y)));
        o.z = 1.0f / (1.0f + __expf(-(a2 + bb.z)));
        o.w = 1.0f / (1.0f + __expf(-(a3 + bb.w)));
        ((float4*)dst_f32)[(size_t)node * 16 + c] = o;
    } else {
        unsigned o = (unsigned)__builtin_amdgcn_cvt_pk_fp8_f32(a0, a1, 0, false);
        o = (unsigned)__builtin_amdgcn_cvt_pk_fp8_f32(a2, a3, (int)o, true);
        ((unsigned*)dst_fp8)[(size_t)node * 16 + c] = o;
    }
}

// ================= launch =================

static inline size_t align16(size_t x) { return (x + 15) & ~(size_t)15; }

extern "C" void kernel_launch(void* const* d_in, const int* in_sizes, int n_in,
                              void* d_out, int out_size, void* d_ws, size_t ws_size,
                              hipStream_t stream) {
    const float* x = (const float*)d_in[0];
    const int* edge_index = (const int*)d_in[1];
    const float* W = (const float*)d_in[2];
    const float* b = (const float*)d_in[3];
    float* out = (float*)d_out;

    const int N = N_NODES;
    const int E = in_sizes[1] / 2;

    const int* row = edge_index;        // source
    const int* col = edge_index + E;    // destination

    char* ws = (char*)d_ws;
    size_t off = 0;
    int* cnt = (int*)(ws + off);             off = align16(off + (size_t)N * 4);
    int* total = (int*)(ws + off);           off = align16(off + 16);
    float* dinv = (float*)(ws + off);        off = align16(off + (size_t)N * 4);
    int* row_start = (int*)(ws + off);       off = align16(off + (size_t)N * 4);
    unsigned* csr = (unsigned*)(ws + off);   off = align16(off + (size_t)(E + 16) * 4);
    unsigned char* y0 = (unsigned char*)(ws + off); off = align16(off + (size_t)N * OUT_C);
    unsigned char* y1 = (unsigned char*)(ws + off); off = align16(off + (size_t)N * OUT_C);
    // eidx lifetime (count -> fill) is disjoint from y1 (gather1 -> gather2): alias.
    unsigned short* eidx = (unsigned short*)y1;   // 1.6MB < 6.4MB

    const int B = 256;
    const int nb_e = (E + B - 1) / B;               // 3125
    const int nb_scan = (N + 511) / 512;            // 196
    const int nb_lin = (N + 63) / 64;               // 1563
    const int lin_half = nb_lin / 2;                // 781 linear groups in count phase
    int nbg_c = (nb_e + 1) / 2;                     // groups of {2 count, 1 linear}
    if (nbg_c < lin_half) nbg_c = lin_half;
    int nbg_f = (nb_e + 1) / 2;                     // groups of {2 fill, 1 linear}
    if (nbg_f < nb_lin - lin_half) nbg_f = nb_lin - lin_half;

    // ---- zero cnt + total counter (contiguous) ----
    hipMemsetAsync(cnt, 0, (size_t)N * 4 + 16, stream);

    // ---- count (+ first half of linear) ----
    count_linear_kernel<<<3 * nbg_c, B, 0, stream>>>(col, cnt, eidx, csr, E,
                                                     x, W, y0, N, lin_half);

    // ---- fused single-pass scan (atomic chunk offsets) ----
    scan_fused_kernel<<<nb_scan, B, 0, stream>>>(cnt, total, row_start, dinv, N);

    // ---- fill (atomic-free) + second half of linear ----
    fill_linear_kernel<<<3 * nbg_f, B, 0, stream>>>(row, col, dinv, row_start, eidx, csr, E,
                                                    x, W, y0, N, lin_half, nb_lin);

    // ---- hop 1 (16 nodes per 256-thread block) ----
    gather_kernel<false><<<(N + 15) / 16, B, 0, stream>>>(y0, y1, nullptr, row_start, cnt, csr, dinv, b, N);

    // ---- hop 2 + bias + sigmoid ----
    gather_kernel<true><<<(N + 15) / 16, B, 0, stream>>>(y1, nullptr, out, row_start, cnt, csr, dinv, b, N);
}